// Round 10
// baseline (221.558 us; speedup 1.0000x reference)
//
#include <hip/hip_runtime.h>

#define HH 512
#define WW 512
#define ROWS 8
#define TR (ROWS + 2)       // 10 staged rows per strip
#define W4 (WW / 4)         // 128 packed words per row
#define CH_STRIDE (HH * WW)
#define IMG_STRIDE (3 * HH * WW)
#define SPB 4               // strips per block
#define NSEG (HH / (ROWS * SPB))  // 16 segments per image
#define CHUNKS (TR * 3 * 2) // 60 × 1KB chunks per image per strip
#define CPW (CHUNKS / 4)    // 15 chunks per wave

#define AS1C const __attribute__((address_space(1))) void
#define AS3  __attribute__((address_space(3))) void

// quantize one channel value: floor(clip(v*255, 0, 255))
__device__ __forceinline__ float quant(float v) {
    return floorf(fminf(fmaxf(v * 255.0f, 0.0f), 255.0f));
}

// pack 4 gray pixels (rounded, cv2 RGB2GRAY weights) into one word.
// KEEP BIT-IDENTICAL to the validated R1/R2 expression.
__device__ __forceinline__ unsigned pack_gray(float4 r, float4 g, float4 b) {
    const unsigned o0 = (unsigned)rintf(0.299f * quant(r.x) + 0.587f * quant(g.x) + 0.114f * quant(b.x));
    const unsigned o1 = (unsigned)rintf(0.299f * quant(r.y) + 0.587f * quant(g.y) + 0.114f * quant(b.y));
    const unsigned o2 = (unsigned)rintf(0.299f * quant(r.z) + 0.587f * quant(g.z) + 0.114f * quant(b.z));
    const unsigned o3 = (unsigned)rintf(0.299f * quant(r.w) + 0.587f * quant(g.w) + 0.114f * quant(b.w));
    return o0 | (o1 << 8) | (o2 << 16) | (o3 << 24);
}

// 4 rounded sobel-avg values (exact integer path) for word w4v of LDS row lr
__device__ __forceinline__ void sobel4(const unsigned* __restrict__ g, int lr, int w4v, int out[4]) {
    const unsigned c0 = g[(lr - 1) * W4 + w4v];
    const unsigned c1 = g[lr * W4 + w4v];
    const unsigned c2 = g[(lr + 1) * W4 + w4v];
    const unsigned lw = g[lr * W4 + (w4v == 0 ? 0 : w4v - 1)];
    const unsigned rw = g[lr * W4 + (w4v == W4 - 1 ? W4 - 1 : w4v + 1)];

    int gx[6];
    gx[0] = (w4v == 0) ? (int)((c1 >> 8) & 255u) : (int)(lw >> 24);
    gx[1] = (int)(c1 & 255u);
    gx[2] = (int)((c1 >> 8) & 255u);
    gx[3] = (int)((c1 >> 16) & 255u);
    gx[4] = (int)(c1 >> 24);
    gx[5] = (w4v == W4 - 1) ? (int)((c1 >> 16) & 255u) : (int)(rw & 255u);

#pragma unroll
    for (int j = 0; j < 4; ++j) {
        const int sx = __builtin_abs(gx[j + 2] - gx[j]);
        const int sy = __builtin_abs((int)((c2 >> (8 * j)) & 255u) - (int)((c0 >> (8 * j)) & 255u));
        const int s = sx + sy;
        out[j] = (s >> 1) + ((s & 1) & ((s >> 1) & 1));   // round-half-even of s/2
    }
}

__global__ __launch_bounds__(256) void sobel_loss_kernel(
    const float* __restrict__ pred, const float* __restrict__ gt_,
    float* __restrict__ out)
{
    // raw staged floats: 60 KB per image; packed gray: 5 KB per image. ~133 KB total.
    __shared__ float    rawP[CHUNKS * 256];
    __shared__ float    rawT[CHUNKS * 256];
    __shared__ unsigned gp[TR * W4];
    __shared__ unsigned gq[TR * W4];
    __shared__ int      red[4];

    const int b   = blockIdx.x >> 4;          // / NSEG
    const int seg = blockIdx.x & (NSEG - 1);

    const float* P = pred + (size_t)b * IMG_STRIDE;
    const float* T = gt_  + (size_t)b * IMG_STRIDE;

    const int wid  = threadIdx.x >> 6;
    const int lane = threadIdx.x & 63;

    // issue this wave's 15 P-chunks then 15 T-chunks of strip s (global_load_lds:
    // per-lane global addr, wave-uniform LDS base, HW writes lane*16B — linear both sides)
    auto issue = [&](int s) {
        const int r0 = (seg * SPB + s) * ROWS;
#pragma unroll
        for (int i = 0; i < CPW; ++i) {
            const int c = wid * CPW + i;
            const int row = c / 6, sub = c % 6, ch = sub >> 1, h = sub & 1;
            int gr = r0 - 1 + row;
            gr = (gr < 0) ? 1 : ((gr > HH - 1) ? 2 * (HH - 1) - gr : gr);
            const float* gsrc = P + ch * CH_STRIDE + gr * WW + h * 256 + lane * 4;
            __builtin_amdgcn_global_load_lds((AS1C*)gsrc, (AS3*)&rawP[c * 256], 16, 0, 0);
        }
#pragma unroll
        for (int i = 0; i < CPW; ++i) {
            const int c = wid * CPW + i;
            const int row = c / 6, sub = c % 6, ch = sub >> 1, h = sub & 1;
            int gr = r0 - 1 + row;
            gr = (gr < 0) ? 1 : ((gr > HH - 1) ? 2 * (HH - 1) - gr : gr);
            const float* gsrc = T + ch * CH_STRIDE + gr * WW + h * 256 + lane * 4;
            __builtin_amdgcn_global_load_lds((AS1C*)gsrc, (AS3*)&rawT[c * 256], 16, 0, 0);
        }
    };

    issue(0);
    int acc = 0;

    for (int s = 0; s < SPB; ++s) {
        // wait until only the 15 T-chunks are outstanding -> all P chunks landed
        asm volatile("s_waitcnt vmcnt(15)" ::: "memory");
        __builtin_amdgcn_s_barrier();                        // B1: P staged; prev sobel done

        // pack P -> gp (1280 words, 5 per thread)
#pragma unroll
        for (int j = 0; j < 5; ++j) {
            const int w = threadIdx.x + j * 256;
            const int row = w >> 7, col = w & 127, h = col >> 6, cc4 = (col & 63) * 4;
            const float4 rr = *reinterpret_cast<const float4*>(&rawP[(row * 6 + 0 + h) * 256 + cc4]);
            const float4 gg = *reinterpret_cast<const float4*>(&rawP[(row * 6 + 2 + h) * 256 + cc4]);
            const float4 bb = *reinterpret_cast<const float4*>(&rawP[(row * 6 + 4 + h) * 256 + cc4]);
            gp[w] = pack_gray(rr, gg, bb);
        }

        asm volatile("s_waitcnt vmcnt(0)" ::: "memory");     // T chunks landed
        asm volatile("s_waitcnt lgkmcnt(0)" ::: "memory");   // gp writes retired
        __builtin_amdgcn_s_barrier();                        // B2

        // pack T -> gq
#pragma unroll
        for (int j = 0; j < 5; ++j) {
            const int w = threadIdx.x + j * 256;
            const int row = w >> 7, col = w & 127, h = col >> 6, cc4 = (col & 63) * 4;
            const float4 rr = *reinterpret_cast<const float4*>(&rawT[(row * 6 + 0 + h) * 256 + cc4]);
            const float4 gg = *reinterpret_cast<const float4*>(&rawT[(row * 6 + 2 + h) * 256 + cc4]);
            const float4 bb = *reinterpret_cast<const float4*>(&rawT[(row * 6 + 4 + h) * 256 + cc4]);
            gq[w] = pack_gray(rr, gg, bb);
        }

        asm volatile("s_waitcnt lgkmcnt(0)" ::: "memory");   // gq writes retired; raw fully consumed
        __builtin_amdgcn_s_barrier();                        // B3

        // prefetch next strip while sobel runs (loads fly across the compute phase)
        if (s + 1 < SPB) issue(s + 1);

        // integer sobel + |diff| accumulate (exact): 1024 words, 4 per thread
#pragma unroll
        for (int j = 0; j < 4; ++j) {
            const int w = threadIdx.x + j * 256;
            const int lr = (w >> 7) + 1, col = w & 127;
            int sp[4], st[4];
            sobel4(gp, lr, col, sp);
            sobel4(gq, lr, col, st);
#pragma unroll
            for (int t2 = 0; t2 < 4; ++t2)
                acc += __builtin_abs(sp[t2] - st[t2]);
        }
    }

    // ---- reduce: wave shuffle, then cross-wave (vmcnt==0 here; plain syncthreads ok) ----
    for (int off = 32; off > 0; off >>= 1)
        acc += __shfl_down(acc, off, 64);

    if (lane == 0) red[wid] = acc;
    __syncthreads();
    if (threadIdx.x == 0) {
        const int s = red[0] + red[1] + red[2] + red[3];
        atomicAdd(out, (float)s * (1.0f / (255.0f * 32.0f * 512.0f * 512.0f)));
    }
}

extern "C" void kernel_launch(void* const* d_in, const int* in_sizes, int n_in,
                              void* d_out, int out_size, void* d_ws, size_t ws_size,
                              hipStream_t stream) {
    const float* y_pred = (const float*)d_in[0];
    const float* y_true = (const float*)d_in[1];
    float* out = (float*)d_out;

    // harness re-poisons d_out with 0xAA before every timed launch
    hipMemsetAsync(out, 0, out_size * sizeof(float), stream);

    const int nblk = 32 * NSEG;   // 512 blocks: one per (batch, 32-row segment)
    sobel_loss_kernel<<<nblk, 256, 0, stream>>>(y_pred, y_true, out);
}